// Round 14
// baseline (641.452 us; speedup 1.0000x reference)
//
#include <hip/hip_runtime.h>

static constexpr int NE   = 4096;      // n_embed
static constexpr int ED   = 64;        // embed_dim
static constexpr int NTOK = 65536;     // 4*16*32*32
static constexpr int NCHUNK = 8;       // code-loop split factor
static constexpr int CPC  = NE / NCHUNK;   // codes per chunk = 512

typedef float  f32x4 __attribute__((ext_vector_type(4)));

// d_out offsets (float elements), outputs concatenated in return order:
// out(4194304), loss(1), perplexity(1), idx(65536), new_embed(262144),
// new_cs(4096), new_ea(262144)
static constexpr long O_OUT  = 0;
static constexpr long O_LOSS = 4194304;
static constexpr long O_PERP = 4194305;
static constexpr long O_IDX  = 4194306;
static constexpr long O_NEMB = 4259842;
static constexpr long O_NCS  = 4521986;
static constexpr long O_NEA  = 4526082;

// ws layout (bytes)
static constexpr size_t W_ACC   = 0;        // double[4]: [0]=loss [1]=n [2]=plog   (zeroed)
static constexpr size_t W_CNT   = 32;       // unsigned[4096] counts                (zeroed)
static constexpr size_t W_CUR   = 16416;    // unsigned[4096] scatter cursors       (zeroed)
static constexpr size_t W_OFF   = 32800;    // unsigned[4096] bucket start offsets
static constexpr size_t W_IDX   = 49184;    // int[65536]
static constexpr size_t W_BKT   = 311328;   // int[65536] token ids bucketed by code
static constexpr size_t W_LOSSP = 573472;   // double[16384] per-block loss partials
static constexpr size_t W_PKD   = 704544;   // uint64[65536] packed (d_bits<<32)|idx
static constexpr size_t W_AUG   = 1228832;  // float[4097*68]: [e row (64), bq, pad(3)] (+1 overrun row)
static constexpr size_t W_ZERO_BYTES = 32800;   // acc + counts + cursors
static constexpr size_t W_PKD_BYTES  = 524288;  // 0xFF-init packed

// ---- augmented codebook: row n = [e_n[0..63], ||e_n||^2, pad] (stride 68) --
__global__ __launch_bounds__(256) void kAug(const float* __restrict__ e,
                                            float* __restrict__ aug) {
    int n = blockIdx.x * 256 + threadIdx.x;        // 0..4095
    const float* er = e + (n << 6);
    float* row = aug + (long)n * 68;
    // bq numerics: identical fmaf 4-partial chain to the 13x-passing kBsq
    float a0 = 0.f, a1 = 0.f, a2 = 0.f, a3 = 0.f;
#pragma unroll
    for (int k = 0; k < ED; k += 4) {
        a0 = fmaf(er[k+0], er[k+0], a0);
        a1 = fmaf(er[k+1], er[k+1], a1);
        a2 = fmaf(er[k+2], er[k+2], a2);
        a3 = fmaf(er[k+3], er[k+3], a3);
    }
#pragma unroll
    for (int k = 0; k < 16; ++k)
        ((f32x4*)row)[k] = ((const f32x4*)er)[k];
    row[64] = (a0 + a1) + (a2 + a3);
}

// ---- asm text helper macros ------------------------------------------------
// z load: dest VGPR, addr = v162 (bumped 0x10000 = one dim stride)
#define ZLD(VD) \
    "global_load_dword v" #VD ", v162, %[zb]\n\t" \
    "v_add_u32 v162, 0x10000, v162\n\t"
// A-sum lines (chain C, z-reg Z)
#define AMUL(C, Z) "v_mul_f32 v" #C ", v" #Z ", v" #Z "\n\t"
#define AFMA(C, Z) "v_fma_f32 v" #C ", v" #Z ", v" #Z ", v" #C "\n\t"
#define AQ4(Z0,Z1,Z2,Z3) AFMA(152,Z0) AFMA(153,Z1) AFMA(154,Z2) AFMA(155,Z3)
#define BQ4(Z0,Z1,Z2,Z3) AFMA(156,Z0) AFMA(157,Z1) AFMA(158,Z2) AFMA(159,Z3)
// dot lines: t0 chain CA (z ZA), t1 chain CB (z ZB), shared e SGPR SR
#define MS2(CA,CB,ZA,ZB,SR) \
    "v_mul_f32 v" #CA ", v" #ZA ", s" #SR "\n\t" \
    "v_mul_f32 v" #CB ", v" #ZB ", s" #SR "\n\t"
#define DS2(CA,CB,ZA,ZB,SR) \
    "v_fma_f32 v" #CA ", v" #ZA ", s" #SR ", v" #CA "\n\t" \
    "v_fma_f32 v" #CB ", v" #ZB ", s" #SR ", v" #CB "\n\t"

// ---- argmin over a 512-code chunk, TWO tokens per thread -------------------
// grid = 1024 blocks: block = (tokenBlock<<3) | chunk; tokens t0 = tb*512+tid,
// t1 = t0+256 (same batch: 16384 % 512 == 0).
// r13 post-mortem: 3-deep LDS pipeline changed NOTHING (491us flat) -> the
// wall is wave-issue cadence (~1 inst/4cyc/wave) x 2 waves/SIMD PLUS the
// CU-shared DS writeback (1KB per broadcast ds_read). Fix: drop LDS entirely;
// e-rows via SMEM s_load into SGPR banks (64B/req, no 64x broadcast waste);
// half-row ping-pong with lgkmcnt(0) placed one 64-FMA burst AFTER the issue
// (r8's flaw was zero prefetch distance; SMEM is OOO so only lgkmcnt(0) is
// legal). Regs top at v162 (~168) -> 3 waves/SIMD; LDS=0.
// Fixed regs: v24-87 z-t0, v88-151 z-t1, v152-155 chains t0, v156-159 chains
// t1, v160 A0, v161 A1, v162 idx counter (also prologue addr tmp).
// SGPRs: s[36:67] bank A (dims 0-31), s[68:99] bank B (dims 32-63) — note
// sreg = 36+k uniformly; s100 bq; s[34:35] row ptr; s33 loop counter.
__global__ __launch_bounds__(256, 3) void kArgmin(const float* __restrict__ z,
                                                  const float* __restrict__ aug,
                                                  unsigned long long* __restrict__ packed) {
    int bid = blockIdx.x;
    int tb = bid >> 3;
    int chunk = bid & 7;

    int t0 = tb * 512 + threadIdx.x;            // token 0
    int t1 = t0 + 256;                          // token 1 (same batch)
    int b  = t0 >> 14;
    int s0 = t0 & 16383;
    unsigned off0 = ((unsigned)b * 1048576u + (unsigned)s0) * 4u;  // byte offset
    unsigned off1 = off0 + 1024u;               // +256 tokens * 4B

    int c0i = chunk * CPC;
    float best0 = __builtin_inff(), best1 = __builtin_inff();
    int bidx0 = c0i, bidx1 = c0i;
    const float* rowPtr = aug + (long)c0i * 68;

    asm volatile(
        // ---- prologue: load z for both tokens (dim stride 0x10000 B) ----
        "v_mov_b32 v162, %[off0]\n\t"
        ZLD(24)  ZLD(25)  ZLD(26)  ZLD(27)  ZLD(28)  ZLD(29)  ZLD(30)  ZLD(31)
        ZLD(32)  ZLD(33)  ZLD(34)  ZLD(35)  ZLD(36)  ZLD(37)  ZLD(38)  ZLD(39)
        ZLD(40)  ZLD(41)  ZLD(42)  ZLD(43)  ZLD(44)  ZLD(45)  ZLD(46)  ZLD(47)
        ZLD(48)  ZLD(49)  ZLD(50)  ZLD(51)  ZLD(52)  ZLD(53)  ZLD(54)  ZLD(55)
        ZLD(56)  ZLD(57)  ZLD(58)  ZLD(59)  ZLD(60)  ZLD(61)  ZLD(62)  ZLD(63)
        ZLD(64)  ZLD(65)  ZLD(66)  ZLD(67)  ZLD(68)  ZLD(69)  ZLD(70)  ZLD(71)
        ZLD(72)  ZLD(73)  ZLD(74)  ZLD(75)  ZLD(76)  ZLD(77)  ZLD(78)  ZLD(79)
        ZLD(80)  ZLD(81)  ZLD(82)  ZLD(83)  ZLD(84)  ZLD(85)  ZLD(86)  ZLD(87)
        "v_mov_b32 v162, %[off1]\n\t"
        ZLD(88)  ZLD(89)  ZLD(90)  ZLD(91)  ZLD(92)  ZLD(93)  ZLD(94)  ZLD(95)
        ZLD(96)  ZLD(97)  ZLD(98)  ZLD(99)  ZLD(100) ZLD(101) ZLD(102) ZLD(103)
        ZLD(104) ZLD(105) ZLD(106) ZLD(107) ZLD(108) ZLD(109) ZLD(110) ZLD(111)
        ZLD(112) ZLD(113) ZLD(114) ZLD(115) ZLD(116) ZLD(117) ZLD(118) ZLD(119)
        ZLD(120) ZLD(121) ZLD(122) ZLD(123) ZLD(124) ZLD(125) ZLD(126) ZLD(127)
        ZLD(128) ZLD(129) ZLD(130) ZLD(131) ZLD(132) ZLD(133) ZLD(134) ZLD(135)
        ZLD(136) ZLD(137) ZLD(138) ZLD(139) ZLD(140) ZLD(141) ZLD(142) ZLD(143)
        ZLD(144) ZLD(145) ZLD(146) ZLD(147) ZLD(148) ZLD(149) ZLD(150) ZLD(151)
        "s_waitcnt vmcnt(0)\n\t"
        // ---- A0 = sum z0^2 (reference 4-partial chain, ascending) ----
        AMUL(152,24) AMUL(153,25) AMUL(154,26) AMUL(155,27)
        AQ4(28,29,30,31)  AQ4(32,33,34,35)  AQ4(36,37,38,39)
        AQ4(40,41,42,43)  AQ4(44,45,46,47)  AQ4(48,49,50,51)
        AQ4(52,53,54,55)  AQ4(56,57,58,59)  AQ4(60,61,62,63)
        AQ4(64,65,66,67)  AQ4(68,69,70,71)  AQ4(72,73,74,75)
        AQ4(76,77,78,79)  AQ4(80,81,82,83)  AQ4(84,85,86,87)
        "v_add_f32 v160, v152, v153\n\t"
        "v_add_f32 v161, v154, v155\n\t"
        "v_add_f32 v160, v160, v161\n\t"          // A0
        // ---- A1 = sum z1^2 ----
        AMUL(156,88) AMUL(157,89) AMUL(158,90) AMUL(159,91)
        BQ4(92,93,94,95)     BQ4(96,97,98,99)     BQ4(100,101,102,103)
        BQ4(104,105,106,107) BQ4(108,109,110,111) BQ4(112,113,114,115)
        BQ4(116,117,118,119) BQ4(120,121,122,123) BQ4(124,125,126,127)
        BQ4(128,129,130,131) BQ4(132,133,134,135) BQ4(136,137,138,139)
        BQ4(140,141,142,143) BQ4(144,145,146,147) BQ4(148,149,150,151)
        "v_add_f32 v161, v156, v157\n\t"
        "v_add_f32 v152, v158, v159\n\t"
        "v_add_f32 v161, v161, v152\n\t"          // A1
        // ---- loop setup: ptr, counters, issue H0(row 0) ----
        "s_mov_b64 s[34:35], %[ap]\n\t"
        "s_mov_b32 s33, 0\n\t"
        "v_mov_b32 v162, %[n0]\n\t"
        "s_load_dwordx16 s[36:51], s[34:35], 0x0\n\t"
        "s_load_dwordx16 s[52:67], s[34:35], 0x40\n\t"
        "1:\n\t"
        // wait H0(r) [issued one burst ago]; issue H1(r)+bq; compute dims 0-31
        "s_waitcnt lgkmcnt(0)\n\t"
        "s_load_dwordx16 s[68:83], s[34:35], 0x80\n\t"
        "s_load_dwordx16 s[84:99], s[34:35], 0xc0\n\t"
        "s_load_dword s100, s[34:35], 0x100\n\t"
        MS2(152,156,24,88,36) MS2(153,157,25,89,37)
        MS2(154,158,26,90,38) MS2(155,159,27,91,39)
        DS2(152,156,28,92,40) DS2(153,157,29,93,41)
        DS2(154,158,30,94,42) DS2(155,159,31,95,43)
        DS2(152,156,32,96,44) DS2(153,157,33,97,45)
        DS2(154,158,34,98,46) DS2(155,159,35,99,47)
        DS2(152,156,36,100,48) DS2(153,157,37,101,49)
        DS2(154,158,38,102,50) DS2(155,159,39,103,51)
        DS2(152,156,40,104,52) DS2(153,157,41,105,53)
        DS2(154,158,42,106,54) DS2(155,159,43,107,55)
        DS2(152,156,44,108,56) DS2(153,157,45,109,57)
        DS2(154,158,46,110,58) DS2(155,159,47,111,59)
        DS2(152,156,48,112,60) DS2(153,157,49,113,61)
        DS2(154,158,50,114,62) DS2(155,159,51,115,63)
        DS2(152,156,52,116,64) DS2(153,157,53,117,65)
        DS2(154,158,54,118,66) DS2(155,159,55,119,67)
        // wait H1(r)+bq; advance ptr; issue H0(r+1); compute dims 32-63
        "s_waitcnt lgkmcnt(0)\n\t"
        "s_add_u32 s34, s34, 272\n\t"
        "s_addc_u32 s35, s35, 0\n\t"
        "s_load_dwordx16 s[36:51], s[34:35], 0x0\n\t"
        "s_load_dwordx16 s[52:67], s[34:35], 0x40\n\t"
        DS2(152,156,56,120,68) DS2(153,157,57,121,69)
        DS2(154,158,58,122,70) DS2(155,159,59,123,71)
        DS2(152,156,60,124,72) DS2(153,157,61,125,73)
        DS2(154,158,62,126,74) DS2(155,159,63,127,75)
        DS2(152,156,64,128,76) DS2(153,157,65,129,77)
        DS2(154,158,66,130,78) DS2(155,159,67,131,79)
        DS2(152,156,68,132,80) DS2(153,157,69,133,81)
        DS2(154,158,70,134,82) DS2(155,159,71,135,83)
        DS2(152,156,72,136,84) DS2(153,157,73,137,85)
        DS2(154,158,74,138,86) DS2(155,159,75,139,87)
        DS2(152,156,76,140,88) DS2(153,157,77,141,89)
        DS2(154,158,78,142,90) DS2(155,159,79,143,91)
        DS2(152,156,80,144,92) DS2(153,157,81,145,93)
        DS2(154,158,82,146,94) DS2(155,159,83,147,95)
        DS2(152,156,84,148,96) DS2(153,157,85,149,97)
        DS2(154,158,86,150,98) DS2(155,159,87,151,99)
        // tails: d = fl((bq+A) - 2*dot), strict-< min track (t0 then t1)
        "v_add_f32 v152, v152, v153\n\t"
        "v_add_f32 v154, v154, v155\n\t"
        "v_add_f32 v152, v152, v154\n\t"
        "v_add_f32 v153, s100, v160\n\t"
        "v_fma_f32 v152, -2.0, v152, v153\n\t"
        "v_cmp_lt_f32 vcc, v152, %[best0]\n\t"
        "v_cndmask_b32 %[best0], %[best0], v152, vcc\n\t"
        "v_cndmask_b32 %[bidx0], %[bidx0], v162, vcc\n\t"
        "v_add_f32 v156, v156, v157\n\t"
        "v_add_f32 v158, v158, v159\n\t"
        "v_add_f32 v156, v156, v158\n\t"
        "v_add_f32 v157, s100, v161\n\t"
        "v_fma_f32 v156, -2.0, v156, v157\n\t"
        "v_cmp_lt_f32 vcc, v156, %[best1]\n\t"
        "v_cndmask_b32 %[best1], %[best1], v156, vcc\n\t"
        "v_cndmask_b32 %[bidx1], %[bidx1], v162, vcc\n\t"
        "v_add_u32 v162, 1, v162\n\t"
        "s_add_u32 s33, s33, 1\n\t"
        "s_cmp_lt_u32 s33, 0x200\n\t"
        "s_cbranch_scc1 1b\n\t"
        "s_waitcnt lgkmcnt(0)\n\t"                 // drain dangling H0 prefetch
        : [best0]"+v"(best0), [bidx0]"+v"(bidx0),
          [best1]"+v"(best1), [bidx1]"+v"(bidx1)
        : [zb]"s"(z), [ap]"s"(rowPtr),
          [off0]"v"(off0), [off1]"v"(off1), [n0]"v"(c0i)
        : "s33","s34","s35",
          "s36","s37","s38","s39","s40","s41","s42","s43",
          "s44","s45","s46","s47","s48","s49","s50","s51",
          "s52","s53","s54","s55","s56","s57","s58","s59",
          "s60","s61","s62","s63","s64","s65","s66","s67",
          "s68","s69","s70","s71","s72","s73","s74","s75",
          "s76","s77","s78","s79","s80","s81","s82","s83",
          "s84","s85","s86","s87","s88","s89","s90","s91",
          "s92","s93","s94","s95","s96","s97","s98","s99",
          "s100",
          "v24","v25","v26","v27","v28","v29","v30","v31",
          "v32","v33","v34","v35","v36","v37","v38","v39",
          "v40","v41","v42","v43","v44","v45","v46","v47",
          "v48","v49","v50","v51","v52","v53","v54","v55",
          "v56","v57","v58","v59","v60","v61","v62","v63",
          "v64","v65","v66","v67","v68","v69","v70","v71",
          "v72","v73","v74","v75","v76","v77","v78","v79",
          "v80","v81","v82","v83","v84","v85","v86","v87",
          "v88","v89","v90","v91","v92","v93","v94","v95",
          "v96","v97","v98","v99","v100","v101","v102","v103",
          "v104","v105","v106","v107","v108","v109","v110","v111",
          "v112","v113","v114","v115","v116","v117","v118","v119",
          "v120","v121","v122","v123","v124","v125","v126","v127",
          "v128","v129","v130","v131","v132","v133","v134","v135",
          "v136","v137","v138","v139","v140","v141","v142","v143",
          "v144","v145","v146","v147","v148","v149","v150","v151",
          "v152","v153","v154","v155","v156","v157","v158","v159",
          "v160","v161","v162",
          "vcc","scc","memory");

    // d >= 0 always so float order == uint order; low 32 bits = idx so
    // equal-d ties pick the smaller index (first-occurrence argmin).
    unsigned long long pk0 =
        ((unsigned long long)__float_as_uint(best0) << 32) | (unsigned)bidx0;
    unsigned long long pk1 =
        ((unsigned long long)__float_as_uint(best1) << 32) | (unsigned)bidx1;
    atomicMin(&packed[t0], pk0);
    atomicMin(&packed[t1], pk1);
}

// ---- unpack chunk-combined argmin, emit idx + counts ----------------------
__global__ __launch_bounds__(256) void kFinish(const unsigned long long* __restrict__ packed,
                                               float* __restrict__ outIdxF,
                                               int* __restrict__ wsIdx,
                                               unsigned* __restrict__ counts) {
    int t = blockIdx.x * 256 + threadIdx.x;
    int idx = (int)(unsigned)(packed[t] & 0xFFFFFFFFull);
    outIdxF[t] = (float)idx;
    wsIdx[t]   = idx;
    atomicAdd(&counts[idx], 1u);
}

// ---- exclusive prefix sum of counts -> bucket offsets ---------------------
__global__ __launch_bounds__(256) void kOffsets(const unsigned* __restrict__ counts,
                                                unsigned* __restrict__ offsets) {
    __shared__ unsigned psum[256];
    int tid = threadIdx.x;
    unsigned local[16];
    unsigned s = 0;
#pragma unroll
    for (int j = 0; j < 16; ++j) { local[j] = s; s += counts[tid * 16 + j]; }
    psum[tid] = s;
    __syncthreads();
    unsigned base = 0;
    for (int i = 0; i < tid; ++i) base += psum[i];
#pragma unroll
    for (int j = 0; j < 16; ++j) offsets[tid * 16 + j] = base + local[j];
}

// ---- scatter token ids into per-code buckets ------------------------------
__global__ __launch_bounds__(256) void kScatter(const int* __restrict__ wsIdx,
                                                const unsigned* __restrict__ offsets,
                                                unsigned* __restrict__ cursor,
                                                int* __restrict__ bucket) {
    int t = blockIdx.x * 256 + threadIdx.x;
    int idx = wsIdx[t];
    unsigned pos = atomicAdd(&cursor[idx], 1u);
    bucket[offsets[idx] + pos] = t;
}

// ---- streaming epilogue: gather, straight-through out, loss partials ------
__global__ __launch_bounds__(256) void kEpilogue(const float* __restrict__ z,
                                                 const float* __restrict__ e,
                                                 const int* __restrict__ wsIdx,
                                                 float* __restrict__ out,
                                                 double* __restrict__ lossPart) {
    __shared__ double lp[4];
    long g = (long)blockIdx.x * 256 + threadIdx.x;   // 0 .. 4194303 (z-linear)
    int b = (int)(g >> 20);
    int r = (int)(g & 1048575);
    int k = r >> 14;
    int s = r & 16383;
    int t = (b << 14) | s;

    float zv = z[g];
    int n = wsIdx[t];
    float eq = e[(n << 6) + k];
    float diff = eq - zv;            // fl(z_q - zp)
    out[g] = zv + diff;              // fl(zp + fl(z_q - zp))  (straight-through)

    double sq = (double)diff * (double)diff;
#pragma unroll
    for (int o = 32; o > 0; o >>= 1) sq += __shfl_down(sq, o);
    if ((threadIdx.x & 63) == 0) lp[threadIdx.x >> 6] = sq;
    __syncthreads();
    if (threadIdx.x == 0) lossPart[blockIdx.x] = (lp[0] + lp[1]) + (lp[2] + lp[3]);
}

// ---- reduce loss partials -------------------------------------------------
__global__ __launch_bounds__(256) void kLoss(const double* __restrict__ lossPart,
                                             double* __restrict__ acc) {
    __shared__ double lp[4];
    double s = 0.0;
    for (int j = 0; j < 64; ++j) s += lossPart[threadIdx.x + j * 256];
#pragma unroll
    for (int o = 32; o > 0; o >>= 1) s += __shfl_down(s, o);
    if ((threadIdx.x & 63) == 0) lp[threadIdx.x >> 6] = s;
    __syncthreads();
    if (threadIdx.x == 0) acc[0] = (lp[0] + lp[1]) + (lp[2] + lp[3]);
}

// ---- EMA part 1: new_cs, n-sum, perplexity partial ------------------------
__global__ __launch_bounds__(256) void kEma1(const float* __restrict__ cs,
                                             const unsigned* __restrict__ counts,
                                             float* __restrict__ outNcs,
                                             double* __restrict__ acc) {
    int n = blockIdx.x * 256 + threadIdx.x;
    float cf = (float)counts[n];
    float p1 = cs[n] * 0.99f;
    float p2 = 0.01f * cf;
    float ncs = p1 + p2;
    outNcs[n] = ncs;
    float p = cf * (1.0f / 65536.0f);          // exact (pow2 divide)
    float term = p * logf(p + 1e-10f);
    double dn = (double)ncs, dt = (double)term;
#pragma unroll
    for (int o = 32; o > 0; o >>= 1) { dn += __shfl_down(dn, o); dt += __shfl_down(dt, o); }
    if ((threadIdx.x & 63) == 0) {
        atomicAdd(&acc[1], dn);
        atomicAdd(&acc[2], dt);
    }
}

// ---- per-code bucket gather: embed_sum -> new_ea, new_embed; scalars ------
__global__ __launch_bounds__(64) void kEsumEma2(const float* __restrict__ z,
                                                const float* __restrict__ ea,
                                                const int* __restrict__ bucket,
                                                const unsigned* __restrict__ offsets,
                                                const unsigned* __restrict__ counts,
                                                const float* __restrict__ ncsArr,
                                                const double* __restrict__ acc,
                                                float* __restrict__ outNemb,
                                                float* __restrict__ outNea,
                                                float* __restrict__ outLoss,
                                                float* __restrict__ outPerp) {
    int n = blockIdx.x;              // code id
    int k = threadIdx.x;             // dim
    unsigned off = offsets[n];
    unsigned cnt = counts[n];
    float es = 0.f;
    for (unsigned i = 0; i < cnt; ++i) {
        int t = bucket[off + i];
        int b = t >> 14;
        int s = t & 16383;
        es += z[(long)b * 1048576 + k * 16384 + s];
    }
    float nea = ea[(n << 6) + k] * 0.99f + 0.01f * es;
    outNea[(n << 6) + k] = nea;
    float nt = (float)acc[1];
    float ncs = ncsArr[n];
    float sc = ((ncs + 1e-5f) / (nt + 0.04096f)) * nt;
    outNemb[(n << 6) + k] = nea / sc;
    if (n == 0 && k == 0) {
        double m = acc[0] / 4194304.0;
        outLoss[0] = 0.25f * (float)m;
        outPerp[0] = (float)exp(-acc[2]);
    }
}

extern "C" void kernel_launch(void* const* d_in, const int* in_sizes, int n_in,
                              void* d_out, int out_size, void* d_ws, size_t ws_size,
                              hipStream_t stream) {
    const float* z  = (const float*)d_in[0];
    const float* ew = (const float*)d_in[1];
    const float* cs = (const float*)d_in[2];
    const float* ea = (const float*)d_in[3];
    float* out = (float*)d_out;
    char* ws = (char*)d_ws;

    double*   acc    = (double*)(ws + W_ACC);
    unsigned* counts = (unsigned*)(ws + W_CNT);
    unsigned* cursor = (unsigned*)(ws + W_CUR);
    unsigned* offs   = (unsigned*)(ws + W_OFF);
    int*      wsIdx  = (int*)(ws + W_IDX);
    int*      bucket = (int*)(ws + W_BKT);
    double*   lossP  = (double*)(ws + W_LOSSP);
    unsigned long long* packed = (unsigned long long*)(ws + W_PKD);
    float*    aug    = (float*)(ws + W_AUG);

    hipMemsetAsync(ws, 0, W_ZERO_BYTES, stream);
    hipMemsetAsync(ws + W_PKD, 0xFF, W_PKD_BYTES, stream);
    kAug<<<NE / 256, 256, 0, stream>>>(ew, aug);
    kArgmin<<<(NTOK / 512) * NCHUNK, 256, 0, stream>>>(z, aug, packed);
    kFinish<<<NTOK / 256, 256, 0, stream>>>(packed, out + O_IDX, wsIdx, counts);
    kOffsets<<<1, 256, 0, stream>>>(counts, offs);
    kScatter<<<NTOK / 256, 256, 0, stream>>>(wsIdx, offs, cursor, bucket);
    kEpilogue<<<16384, 256, 0, stream>>>(z, ew, wsIdx, out + O_OUT, lossP);
    kLoss<<<1, 256, 0, stream>>>(lossP, acc);
    kEma1<<<NE / 256, 256, 0, stream>>>(cs, counts, out + O_NCS, acc);
    kEsumEma2<<<NE, 64, 0, stream>>>(z, ea, bucket, offs, counts, out + O_NCS, acc,
                                     out + O_NEMB, out + O_NEA,
                                     out + O_LOSS, out + O_PERP);
}